// Round 1
// baseline (151.893 us; speedup 1.0000x reference)
//
#include <hip/hip_runtime.h>
#include <math.h>

#define BB 32
#define NIN 2048
#define NOUT 64
#define DD 16
// row = NOUT*DD = 1024 floats = 256 float4

__device__ __forceinline__ float dot4(float4 a, float4 b) {
    return fmaf(a.x, b.x, fmaf(a.y, b.y, fmaf(a.z, b.z, a.w * b.w)));
}

// MODE 0: uniform weights (just sum). MODE 1: logits = dot(x,v0).
// MODE 2: logits = dot(x,v0)+dot(x,v1).
template <int MODE>
__global__ __launch_bounds__(256) void pass_kernel(
    const float* __restrict__ x,
    const float* __restrict__ v0,
    const float* __restrict__ v1,
    float4* __restrict__ partials,   // [B][nchunks][256] float4  == [B][nchunks][n_out][d]
    int nchunks, int rpc)
{
    const int chunk = blockIdx.x;
    const int b     = blockIdx.y;
    const int tid   = threadIdx.x;
    const int lane  = tid & 63;
    const int wave  = tid >> 6;
    const int g     = lane >> 2;   // n_out sub-index within a j-group
    const int q     = lane & 3;    // d-quarter

    float4 va[4], vb[4];
    if (MODE >= 1) {
        #pragma unroll
        for (int j = 0; j < 4; ++j) {
            const int n_out = 16 * j + g;
            va[j] = *(const float4*)(v0 + ((size_t)(b * NOUT + n_out)) * DD + 4 * q);
            if (MODE == 2)
                vb[j] = *(const float4*)(v1 + ((size_t)(b * NOUT + n_out)) * DD + 4 * q);
        }
    }

    float4 acc[4];
    #pragma unroll
    for (int j = 0; j < 4; ++j) acc[j] = make_float4(0.f, 0.f, 0.f, 0.f);

    const int row0 = chunk * rpc;
    for (int r = wave; r < rpc; r += 4) {
        const float4* rp = (const float4*)x + ((size_t)(b * NIN) + row0 + r) * 256;
        float4 xj[4];
        #pragma unroll
        for (int j = 0; j < 4; ++j) xj[j] = rp[j * 64 + lane];

        if (MODE == 0) {
            #pragma unroll
            for (int j = 0; j < 4; ++j) {
                acc[j].x += xj[j].x; acc[j].y += xj[j].y;
                acc[j].z += xj[j].z; acc[j].w += xj[j].w;
            }
        } else {
            float l[4];
            #pragma unroll
            for (int j = 0; j < 4; ++j) {
                float d0 = dot4(xj[j], va[j]);
                if (MODE == 2) d0 += dot4(xj[j], vb[j]);
                d0 += __shfl_xor(d0, 1);
                d0 += __shfl_xor(d0, 2);
                l[j] = d0;                  // logit for n_out = 16*j + g (replicated in quad)
            }
            float m = fmaxf(fmaxf(l[0], l[1]), fmaxf(l[2], l[3]));
            m = fmaxf(m, __shfl_xor(m, 4));
            m = fmaxf(m, __shfl_xor(m, 8));
            m = fmaxf(m, __shfl_xor(m, 16));
            m = fmaxf(m, __shfl_xor(m, 32));
            float e[4], p = 0.f;
            #pragma unroll
            for (int j = 0; j < 4; ++j) { e[j] = __expf(l[j] - m); p += e[j]; }
            p += __shfl_xor(p, 4);
            p += __shfl_xor(p, 8);
            p += __shfl_xor(p, 16);
            p += __shfl_xor(p, 32);        // full 64-way denom (each n_out counted once)
            const float inv = 1.0f / p;
            #pragma unroll
            for (int j = 0; j < 4; ++j) {
                const float a = e[j] * inv;
                acc[j].x = fmaf(xj[j].x, a, acc[j].x);
                acc[j].y = fmaf(xj[j].y, a, acc[j].y);
                acc[j].z = fmaf(xj[j].z, a, acc[j].z);
                acc[j].w = fmaf(xj[j].w, a, acc[j].w);
            }
        }
    }

    // cross-wave reduce: lds[wave][j*64+lane] is exactly the [n_out][d] layout
    __shared__ float4 lds[4][256];
    #pragma unroll
    for (int j = 0; j < 4; ++j) lds[wave][j * 64 + lane] = acc[j];
    __syncthreads();
    float4 r0 = lds[0][tid], r1 = lds[1][tid], r2 = lds[2][tid], r3 = lds[3][tid];
    float4 s;
    s.x = (r0.x + r1.x) + (r2.x + r3.x);
    s.y = (r0.y + r1.y) + (r2.y + r3.y);
    s.z = (r0.z + r1.z) + (r2.z + r3.z);
    s.w = (r0.w + r1.w) + (r2.w + r3.w);
    partials[((size_t)(b * nchunks + chunk)) * 256 + tid] = s;
}

// One wave per (b, n_out): sum partials over chunks, scale, +bias, squash.
__global__ __launch_bounds__(256) void reduce_squash_kernel(
    const float* __restrict__ partials,
    const float* __restrict__ bias,
    float* __restrict__ vout,
    int nchunks, float scale)
{
    const int wid  = blockIdx.x * 4 + (threadIdx.x >> 6);  // 0 .. B*NOUT-1
    const int lane = threadIdx.x & 63;
    const int b    = wid >> 6;
    const int n_out = wid & 63;
    const int d    = lane & 15;
    const int g    = lane >> 4;

    float sum = 0.f;
    for (int c = g; c < nchunks; c += 4)
        sum += partials[((size_t)(b * nchunks + c)) * 1024 + n_out * 16 + d];
    sum += __shfl_xor(sum, 16);
    sum += __shfl_xor(sum, 32);

    const float s  = fmaf(sum, scale, bias[n_out * 16 + d]);
    float n2 = s * s;
    n2 += __shfl_xor(n2, 1);
    n2 += __shfl_xor(n2, 2);
    n2 += __shfl_xor(n2, 4);
    n2 += __shfl_xor(n2, 8);
    const float out = s * (n2 / (1.0f + n2)) / sqrtf(n2 + 1e-7f);
    if (g == 0) vout[((size_t)(b * NOUT) + n_out) * DD + d] = out;
}

extern "C" void kernel_launch(void* const* d_in, const int* in_sizes, int n_in,
                              void* d_out, int out_size, void* d_ws, size_t ws_size,
                              hipStream_t stream) {
    const float* x    = (const float*)d_in[0];
    const float* bias = (const float*)d_in[1];
    float* out        = (float*)d_out;

    // pick chunk count so partials + v0 + v1 fit in ws
    int CH = 64;
    {
        auto need = [](int ch) { return ((size_t)BB * ch * 1024 + 2 * (size_t)BB * NOUT * DD) * sizeof(float); };
        if (ws_size < need(64)) CH = 16;
        if (ws_size < need(16)) CH = 4;
    }
    const int rpc = NIN / CH;

    float* partials = (float*)d_ws;
    float* v0 = partials + (size_t)BB * CH * 1024;
    float* v1 = v0 + (size_t)BB * NOUT * DD;

    dim3 grid(CH, BB);
    const int rgrid = (BB * NOUT) / 4;  // 512 blocks of 4 waves

    // iter 0
    pass_kernel<0><<<grid, 256, 0, stream>>>(x, nullptr, nullptr, (float4*)partials, CH, rpc);
    reduce_squash_kernel<<<rgrid, 256, 0, stream>>>(partials, bias, v0, CH, 1.0f / 64.0f);
    // iter 1
    pass_kernel<1><<<grid, 256, 0, stream>>>(x, v0, nullptr, (float4*)partials, CH, rpc);
    reduce_squash_kernel<<<rgrid, 256, 0, stream>>>(partials, bias, v1, CH, 1.0f);
    // iter 2
    pass_kernel<2><<<grid, 256, 0, stream>>>(x, v0, v1, (float4*)partials, CH, rpc);
    reduce_squash_kernel<<<rgrid, 256, 0, stream>>>(partials, bias, out, CH, 1.0f);
}